// Round 2
// baseline (2232.836 us; speedup 1.0000x reference)
//
#include <hip/hip_runtime.h>
#include <hip/hip_bf16.h>
#include <stdint.h>

typedef float f32x4 __attribute__((ext_vector_type(4)));
typedef short s16x8 __attribute__((ext_vector_type(8)));

#define INV_SCALE (1.0f / 1024.0f)  // W pre-scaled x64, h x16

__device__ __forceinline__ float sigm(float x) {
  return __builtin_amdgcn_rcpf(1.f + __builtin_amdgcn_exp2f(-1.4426950408889634f * x));
}
__device__ __forceinline__ float tanh_(float x) {
  return 1.f - 2.f * __builtin_amdgcn_rcpf(__builtin_amdgcn_exp2f(2.8853900817779268f * x) + 1.f);
}
__device__ __forceinline__ ushort f2bf(float f) {
  union { float f; uint32_t u; } v; v.f = f;
  return (ushort)((v.u + 0x7FFFu + ((v.u >> 16) & 1)) >> 16);
}
__device__ __forceinline__ float bf2f(ushort b) {
  union { uint32_t u; float f; } v; v.u = ((uint32_t)b) << 16; return v.f;
}

// ---------------- prep: converts + permutes + transposes ----------------
__global__ __launch_bounds__(256) void prep_kernel(
    const float* __restrict__ emb, const int* __restrict__ x,
    const float* __restrict__ Wih0, const float* __restrict__ Wih1,
    const float* __restrict__ bih0, const float* __restrict__ bhh0,
    const float* __restrict__ bih1, const float* __restrict__ bhh1,
    ushort* __restrict__ emb_bf, int* __restrict__ idx_ws,
    ushort* __restrict__ W0p, ushort* __restrict__ W1p,
    float* __restrict__ b0p, float* __restrict__ b1p)
{
  const int stride = gridDim.x * blockDim.x;
  const int gid = blockIdx.x * blockDim.x + threadIdx.x;
  for (int i = gid; i < 32000 * 128; i += stride) emb_bf[i] = f2bf(emb[i]);
  // idx_ws[t*128+b] = x[b*512+t]
  for (int i = gid; i < 65536; i += stride) idx_ws[i] = x[(i & 127) * 512 + (i >> 7)];
  // W0p[j][k] = Wih0[(j&3)*256 + (j>>2)][k]   (j = hid*4 + gate)
  for (int i = gid; i < 1024 * 128; i += stride) {
    int j = i >> 7, k = i & 127;
    int p = ((j & 3) << 8) | (j >> 2);
    W0p[i] = f2bf(Wih0[p * 128 + k]);
  }
  for (int i = gid; i < 1024 * 256; i += stride) {
    int j = i >> 8, k = i & 255;
    int p = ((j & 3) << 8) | (j >> 2);
    W1p[i] = f2bf(Wih1[p * 256 + k]);
  }
  for (int i = gid; i < 1024; i += stride) {
    int p = ((i & 3) << 8) | (i >> 2);
    b0p[i] = bih0[p] + bhh0[p];
    b1p[i] = bih1[p] + bhh1[p];
  }
}

// ---------------- wide GEMM: xp[m][j] = A[m,:] @ Wp[j,:]^T + bias[j] ----------------
// M=65536 (m = t*128+b), N=1024 (interleaved j), K = 128 or 256. bf16 MFMA.
template <int KD, bool GATHER>
__global__ __launch_bounds__(256) void gemm_xp(
    const ushort* __restrict__ A, const int* __restrict__ idx,
    const ushort* __restrict__ B, const float* __restrict__ bias,
    ushort* __restrict__ out)
{
  __shared__ ushort Al[128 * 72];
  __shared__ ushort Bl[128 * 72];
  const int tid = threadIdx.x;
  const int l = tid & 63, w = tid >> 6;
  const int wm = w >> 1, wn = w & 1;
  const int lr = l & 15, lg = l >> 4;
  const int m0 = blockIdx.x * 128, n0 = blockIdx.y * 128;

  f32x4 acc[4][4];
#pragma unroll
  for (int a = 0; a < 4; ++a)
#pragma unroll
    for (int b = 0; b < 4; ++b) acc[a][b] = (f32x4)0.f;

  const int srow = tid >> 1, sseg = tid & 1;
  for (int kk = 0; kk < KD / 64; ++kk) {
    const int k0 = kk * 64;
    size_t arow = GATHER ? (size_t)idx[m0 + srow] : (size_t)(m0 + srow);
    const uint4* sa = (const uint4*)(A + arow * KD + k0 + sseg * 32);
    uint4* da = (uint4*)(Al + srow * 72 + sseg * 32);
    da[0] = sa[0]; da[1] = sa[1]; da[2] = sa[2]; da[3] = sa[3];
    const uint4* sb = (const uint4*)(B + (size_t)(n0 + srow) * KD + k0 + sseg * 32);
    uint4* db = (uint4*)(Bl + srow * 72 + sseg * 32);
    db[0] = sb[0]; db[1] = sb[1]; db[2] = sb[2]; db[3] = sb[3];
    __syncthreads();
#pragma unroll
    for (int ks = 0; ks < 2; ++ks) {
      s16x8 av[4], bv[4];
#pragma unroll
      for (int mt = 0; mt < 4; ++mt)
        av[mt] = *(const s16x8*)(Al + (wm * 64 + mt * 16 + lr) * 72 + ks * 32 + lg * 8);
#pragma unroll
      for (int nt = 0; nt < 4; ++nt)
        bv[nt] = *(const s16x8*)(Bl + (wn * 64 + nt * 16 + lr) * 72 + ks * 32 + lg * 8);
#pragma unroll
      for (int mt = 0; mt < 4; ++mt)
#pragma unroll
        for (int nt = 0; nt < 4; ++nt)
          acc[mt][nt] = __builtin_amdgcn_mfma_f32_16x16x32_bf16(av[mt], bv[nt], acc[mt][nt], 0, 0, 0);
    }
    __syncthreads();
  }

#pragma unroll
  for (int nt = 0; nt < 4; ++nt) {
    const int colg = n0 + wn * 64 + nt * 16 + lr;
    const float bv = bias[colg];
#pragma unroll
    for (int mt = 0; mt < 4; ++mt) {
#pragma unroll
      for (int i = 0; i < 4; ++i) {
        const int rowg = m0 + wm * 64 + mt * 16 + 4 * lg + i;
        out[(size_t)rowg * 1024 + colg] = f2bf(acc[mt][nt][i] + bv);
      }
    }
  }
}

// ---------------- LSTM scan: one WG = 16 batches, all 512 steps ----------------
// W_hh held register-resident as fp8 e4m3 (x64). h exchanged via LDS as fp8 (x16).
// 16 waves; wave w owns gate tiles {w, w+16, w+32, w+48} = hidden cols [16w,16w+16) x {i,f,g,o}.
template <bool FINAL>
__global__ __launch_bounds__(1024) void lstm_scan(
    const ushort* __restrict__ xp, const float* __restrict__ Whh,
    ushort* __restrict__ hs_out, const float* __restrict__ fcw,
    const float* __restrict__ fcb, float* __restrict__ out)
{
  __shared__ unsigned char hb[2][16 * 272];  // [buf][batch-row][hidden fp8], pad 272
  __shared__ float hf[16 * 257];             // final-step f32 h (FINAL only)
  const int tid = threadIdx.x;
  const int l = tid & 63, w = tid >> 6;
  const int lr = l & 15, lg = l >> 4;
  const int b0 = blockIdx.x * 16;
  const int hcol = 16 * w + lr;

  // Load W_hh fragments -> registers (fp8, x64). B-frag: n = 16*w+256*s+lr, k = ks*32+lg*8+j
  long wf[4][8];
#pragma unroll
  for (int s = 0; s < 4; ++s) {
    const int n = 16 * w + 256 * s + lr;
#pragma unroll
    for (int ks = 0; ks < 8; ++ks) {
      const f32x4* p = (const f32x4*)(Whh + (size_t)n * 256 + ks * 32 + lg * 8);
      f32x4 w0 = p[0], w1 = p[1];
      int d0 = __builtin_amdgcn_cvt_pk_fp8_f32(w0.x * 64.f, w0.y * 64.f, 0, false);
      d0 = __builtin_amdgcn_cvt_pk_fp8_f32(w0.z * 64.f, w0.w * 64.f, d0, true);
      int d1 = __builtin_amdgcn_cvt_pk_fp8_f32(w1.x * 64.f, w1.y * 64.f, 0, false);
      d1 = __builtin_amdgcn_cvt_pk_fp8_f32(w1.z * 64.f, w1.w * 64.f, d1, true);
      wf[s][ks] = (long)(((unsigned long long)(unsigned)d1 << 32) | (unsigned)d0);
    }
  }

  for (int i2 = tid; i2 < 2 * 16 * 272; i2 += 1024) ((unsigned char*)hb)[i2] = 0;

  float cc[4] = {0.f, 0.f, 0.f, 0.f};
  uint2 xpA[4];
#pragma unroll
  for (int i = 0; i < 4; ++i)
    xpA[i] = *(const uint2*)(xp + (size_t)(b0 + 4 * lg + i) * 1024 + hcol * 4);
  __syncthreads();

  for (int t = 0; t < 512; ++t) {
    const unsigned char* hr = hb[t & 1];
    unsigned char* hw = hb[(t & 1) ^ 1];
    f32x4 acc0 = (f32x4)0.f, acc1 = (f32x4)0.f, acc2 = (f32x4)0.f, acc3 = (f32x4)0.f;
#pragma unroll
    for (int ks = 0; ks < 8; ++ks) {
      uint2 av = *(const uint2*)(hr + lr * 272 + ks * 32 + lg * 8);
      long a = (long)(((unsigned long long)av.y << 32) | av.x);
      acc0 = __builtin_amdgcn_mfma_f32_16x16x32_fp8_fp8(a, wf[0][ks], acc0, 0, 0, 0);
      acc1 = __builtin_amdgcn_mfma_f32_16x16x32_fp8_fp8(a, wf[1][ks], acc1, 0, 0, 0);
      acc2 = __builtin_amdgcn_mfma_f32_16x16x32_fp8_fp8(a, wf[2][ks], acc2, 0, 0, 0);
      acc3 = __builtin_amdgcn_mfma_f32_16x16x32_fp8_fp8(a, wf[3][ks], acc3, 0, 0, 0);
    }
#pragma unroll
    for (int i = 0; i < 4; ++i) {
      const int row = 4 * lg + i;
      union { uint2 u; ushort s[4]; } xv; xv.u = xpA[i];
      float gi = acc0[i] * INV_SCALE + bf2f(xv.s[0]);
      float gf = acc1[i] * INV_SCALE + bf2f(xv.s[1]);
      float gg = acc2[i] * INV_SCALE + bf2f(xv.s[2]);
      float go = acc3[i] * INV_SCALE + bf2f(xv.s[3]);
      float si = sigm(gi), sf = sigm(gf), so = sigm(go);
      float tg = tanh_(gg);
      cc[i] = sf * cc[i] + si * tg;
      float h = so * tanh_(cc[i]);
      int q = __builtin_amdgcn_cvt_pk_fp8_f32(h * 16.f, h * 16.f, 0, false);
      hw[row * 272 + hcol] = (unsigned char)(q & 0xFF);
      if (!FINAL) {
        hs_out[((size_t)t * 128 + b0 + row) * 256 + hcol] = f2bf(h);
      } else if (t == 511) {
        hf[row * 257 + hcol] = h;
      }
    }
    if (t < 511) {
#pragma unroll
      for (int i = 0; i < 4; ++i)
        xpA[i] = *(const uint2*)(xp + ((size_t)(t + 1) * 128 + b0 + 4 * lg + i) * 1024 + hcol * 4);
    }
    __syncthreads();
  }

  if (FINAL && tid < 64) {
    const int b = lr, ch = lg;
    float s = 0.f;
#pragma unroll 8
    for (int k = 0; k < 64; ++k) {
      const int kk2 = ch * 64 + k;
      s += hf[b * 257 + kk2] * fcw[kk2];
    }
    s += __shfl_xor(s, 16);
    s += __shfl_xor(s, 32);
    if (l < 16) out[b0 + b] = sigm(s + fcb[0]);
  }
}

// ---------------- launch ----------------
extern "C" void kernel_launch(void* const* d_in, const int* in_sizes, int n_in,
                              void* d_out, int out_size, void* d_ws, size_t ws_size,
                              hipStream_t stream)
{
  const int*   x    = (const int*)d_in[0];
  const float* emb  = (const float*)d_in[1];
  const float* fcw  = (const float*)d_in[2];
  const float* fcb  = (const float*)d_in[3];
  const float* Wih0 = (const float*)d_in[4];
  const float* Whh0 = (const float*)d_in[5];
  const float* bih0 = (const float*)d_in[6];
  const float* bhh0 = (const float*)d_in[7];
  const float* Wih1 = (const float*)d_in[8];
  const float* Whh1 = (const float*)d_in[9];
  const float* bih1 = (const float*)d_in[10];
  const float* bhh1 = (const float*)d_in[11];

  char* ws = (char*)d_ws;
  size_t off = 0;
  auto alloc = [&](size_t bytes) {
    void* p = ws + off;
    off = (off + bytes + 255) & ~(size_t)255;
    return p;
  };
  ushort* xp_ws  = (ushort*)alloc(65536ull * 1024 * 2);  // reused for xp0' then xp1'
  ushort* hs0    = (ushort*)alloc(65536ull * 256 * 2);
  ushort* emb_bf = (ushort*)alloc(32000ull * 128 * 2);
  ushort* W0p    = (ushort*)alloc(1024ull * 128 * 2);
  ushort* W1p    = (ushort*)alloc(1024ull * 256 * 2);
  float*  b0p    = (float*)alloc(1024 * 4);
  float*  b1p    = (float*)alloc(1024 * 4);
  int*    idx_ws = (int*)alloc(65536 * 4);

  prep_kernel<<<512, 256, 0, stream>>>(emb, x, Wih0, Wih1, bih0, bhh0, bih1, bhh1,
                                       emb_bf, idx_ws, W0p, W1p, b0p, b1p);
  gemm_xp<128, true><<<dim3(512, 8), 256, 0, stream>>>(emb_bf, idx_ws, W0p, b0p, xp_ws);
  lstm_scan<false><<<8, 1024, 0, stream>>>(xp_ws, Whh0, hs0, nullptr, nullptr, nullptr);
  gemm_xp<256, false><<<dim3(512, 8), 256, 0, stream>>>(hs0, nullptr, W1p, b1p, xp_ws);
  lstm_scan<true><<<8, 1024, 0, stream>>>(xp_ws, Whh1, nullptr, fcw, fcb, (float*)d_out);
}

// Round 3
// 1908.242 us; speedup vs baseline: 1.1701x; 1.1701x over previous
//
#include <hip/hip_runtime.h>
#include <hip/hip_bf16.h>
#include <stdint.h>

typedef float f32x4 __attribute__((ext_vector_type(4)));
typedef short s16x8 __attribute__((ext_vector_type(8)));

#define INV_SCALE (1.0f / 1024.0f)  // W pre-scaled x64, h x16

__device__ __forceinline__ float sigm(float x) {
  return __builtin_amdgcn_rcpf(1.f + __builtin_amdgcn_exp2f(-1.4426950408889634f * x));
}
__device__ __forceinline__ float tanh_(float x) {
  return 1.f - 2.f * __builtin_amdgcn_rcpf(__builtin_amdgcn_exp2f(2.8853900817779268f * x) + 1.f);
}
__device__ __forceinline__ ushort f2bf(float f) {
  union { float f; uint32_t u; } v; v.f = f;
  return (ushort)((v.u + 0x7FFFu + ((v.u >> 16) & 1)) >> 16);
}
__device__ __forceinline__ float bf2f(ushort b) {
  union { uint32_t u; float f; } v; v.u = ((uint32_t)b) << 16; return v.f;
}

// ---------------- prep: converts + permutes + transposes ----------------
__global__ __launch_bounds__(256) void prep_kernel(
    const float* __restrict__ emb, const int* __restrict__ x,
    const float* __restrict__ Wih0, const float* __restrict__ Wih1,
    const float* __restrict__ bih0, const float* __restrict__ bhh0,
    const float* __restrict__ bih1, const float* __restrict__ bhh1,
    ushort* __restrict__ emb_bf, int* __restrict__ idx_ws,
    ushort* __restrict__ W0p, ushort* __restrict__ W1p,
    float* __restrict__ b0p, float* __restrict__ b1p)
{
  const int stride = gridDim.x * blockDim.x;
  const int gid = blockIdx.x * blockDim.x + threadIdx.x;
  for (int i = gid; i < 32000 * 128; i += stride) emb_bf[i] = f2bf(emb[i]);
  // idx_ws[t*128+b] = x[b*512+t]
  for (int i = gid; i < 65536; i += stride) idx_ws[i] = x[(i & 127) * 512 + (i >> 7)];
  // W0p[j][k] = Wih0[(j&3)*256 + (j>>2)][k]   (j = hid*4 + gate)
  for (int i = gid; i < 1024 * 128; i += stride) {
    int j = i >> 7, k = i & 127;
    int p = ((j & 3) << 8) | (j >> 2);
    W0p[i] = f2bf(Wih0[p * 128 + k]);
  }
  for (int i = gid; i < 1024 * 256; i += stride) {
    int j = i >> 8, k = i & 255;
    int p = ((j & 3) << 8) | (j >> 2);
    W1p[i] = f2bf(Wih1[p * 256 + k]);
  }
  for (int i = gid; i < 1024; i += stride) {
    int p = ((i & 3) << 8) | (i >> 2);
    b0p[i] = bih0[p] + bhh0[p];
    b1p[i] = bih1[p] + bhh1[p];
  }
}

// ---------------- wide GEMM: xp[m][j] = A[m,:] @ Wp[j,:]^T + bias[j] ----------------
// M=65536 (m = t*128+b), N=1024 (interleaved j), K = 128 or 256. bf16 MFMA.
template <int KD, bool GATHER>
__global__ __launch_bounds__(256) void gemm_xp(
    const ushort* __restrict__ A, const int* __restrict__ idx,
    const ushort* __restrict__ B, const float* __restrict__ bias,
    ushort* __restrict__ out)
{
  __shared__ ushort Al[128 * 72];
  __shared__ ushort Bl[128 * 72];
  const int tid = threadIdx.x;
  const int l = tid & 63, w = tid >> 6;
  const int wm = w >> 1, wn = w & 1;
  const int lr = l & 15, lg = l >> 4;
  const int m0 = blockIdx.x * 128, n0 = blockIdx.y * 128;

  f32x4 acc[4][4];
#pragma unroll
  for (int a = 0; a < 4; ++a)
#pragma unroll
    for (int b = 0; b < 4; ++b) acc[a][b] = (f32x4)0.f;

  const int srow = tid >> 1, sseg = tid & 1;
  for (int kk = 0; kk < KD / 64; ++kk) {
    const int k0 = kk * 64;
    size_t arow = GATHER ? (size_t)idx[m0 + srow] : (size_t)(m0 + srow);
    const uint4* sa = (const uint4*)(A + arow * KD + k0 + sseg * 32);
    uint4* da = (uint4*)(Al + srow * 72 + sseg * 32);
    da[0] = sa[0]; da[1] = sa[1]; da[2] = sa[2]; da[3] = sa[3];
    const uint4* sb = (const uint4*)(B + (size_t)(n0 + srow) * KD + k0 + sseg * 32);
    uint4* db = (uint4*)(Bl + srow * 72 + sseg * 32);
    db[0] = sb[0]; db[1] = sb[1]; db[2] = sb[2]; db[3] = sb[3];
    __syncthreads();
#pragma unroll
    for (int ks = 0; ks < 2; ++ks) {
      s16x8 av[4], bv[4];
#pragma unroll
      for (int mt = 0; mt < 4; ++mt)
        av[mt] = *(const s16x8*)(Al + (wm * 64 + mt * 16 + lr) * 72 + ks * 32 + lg * 8);
#pragma unroll
      for (int nt = 0; nt < 4; ++nt)
        bv[nt] = *(const s16x8*)(Bl + (wn * 64 + nt * 16 + lr) * 72 + ks * 32 + lg * 8);
#pragma unroll
      for (int mt = 0; mt < 4; ++mt)
#pragma unroll
        for (int nt = 0; nt < 4; ++nt)
          acc[mt][nt] = __builtin_amdgcn_mfma_f32_16x16x32_bf16(av[mt], bv[nt], acc[mt][nt], 0, 0, 0);
    }
    __syncthreads();
  }

#pragma unroll
  for (int nt = 0; nt < 4; ++nt) {
    const int colg = n0 + wn * 64 + nt * 16 + lr;
    const float bv = bias[colg];
#pragma unroll
    for (int mt = 0; mt < 4; ++mt) {
#pragma unroll
      for (int i = 0; i < 4; ++i) {
        const int rowg = m0 + wm * 64 + mt * 16 + 4 * lg + i;
        out[(size_t)rowg * 1024 + colg] = f2bf(acc[mt][nt][i] + bv);
      }
    }
  }
}

// ---------------- LSTM scan: one WG = 4 batches, all 512 steps, 32 WGs ----------------
// W_hh register-resident as fp8 e4m3 (x64). h exchanged via LDS as fp8 (x16).
// MFMA phase: wave w owns hcol tile [16w,16w+16) x 4 gate-segments; batch rows 0-3 valid,
// rows 4-15 read zeros. Gate phase: acc redistributed via LDS so EVERY lane does exactly
// one (batch, hcol) cell's nonlinearity — spreads the trans-bound work over 4x the CUs.
template <bool FINAL>
__global__ __launch_bounds__(1024) void lstm_scan(
    const ushort* __restrict__ xp, const float* __restrict__ Whh,
    ushort* __restrict__ hs_out, const float* __restrict__ fcw,
    const float* __restrict__ fcb, float* __restrict__ out)
{
  __shared__ unsigned char hb[2][16 * 272];  // [buf][batch-row][hidden fp8], pad 272
  __shared__ float gl[4 * 256 * 4];          // [row][hcol][gate] f32
  __shared__ float hf[4][260];               // final-step f32 h (FINAL only)
  const int tid = threadIdx.x;
  const int l = tid & 63, w = tid >> 6;
  const int lr = l & 15, lg = l >> 4;
  const int b0 = blockIdx.x * 4;
  const int hcol = 16 * w + lr;   // MFMA-phase column
  const int cb = tid >> 8;        // gate-phase batch row 0..3
  const int ch = tid & 255;       // gate-phase hidden col

  // Load W_hh fragments -> registers (fp8, x64). B-frag: n = gate*256 + hcol, k = ks*32+lg*8+j
  long wf[4][8];
#pragma unroll
  for (int s = 0; s < 4; ++s) {
    const int n = 256 * s + hcol;
#pragma unroll
    for (int ks = 0; ks < 8; ++ks) {
      const f32x4* p = (const f32x4*)(Whh + (size_t)n * 256 + ks * 32 + lg * 8);
      f32x4 w0 = p[0], w1 = p[1];
      int d0 = __builtin_amdgcn_cvt_pk_fp8_f32(w0.x * 64.f, w0.y * 64.f, 0, false);
      d0 = __builtin_amdgcn_cvt_pk_fp8_f32(w0.z * 64.f, w0.w * 64.f, d0, true);
      int d1 = __builtin_amdgcn_cvt_pk_fp8_f32(w1.x * 64.f, w1.y * 64.f, 0, false);
      d1 = __builtin_amdgcn_cvt_pk_fp8_f32(w1.z * 64.f, w1.w * 64.f, d1, true);
      wf[s][ks] = (long)(((unsigned long long)(unsigned)d1 << 32) | (unsigned)d0);
    }
  }

  for (int i2 = tid; i2 < 2 * 16 * 272; i2 += 1024) ((unsigned char*)hb)[i2] = 0;

  float cc = 0.f;
  uint2 xpv = *(const uint2*)(xp + (size_t)(b0 + cb) * 1024 + ch * 4);
  __syncthreads();

  for (int t = 0; t < 512; ++t) {
    const unsigned char* hr = hb[t & 1];
    unsigned char* hw = hb[(t & 1) ^ 1];
    // ---- MFMA phase ----
    f32x4 acc0 = (f32x4)0.f, acc1 = (f32x4)0.f, acc2 = (f32x4)0.f, acc3 = (f32x4)0.f;
#pragma unroll
    for (int ks = 0; ks < 8; ++ks) {
      uint2 av = *(const uint2*)(hr + lr * 272 + ks * 32 + lg * 8);
      long a = (long)(((unsigned long long)av.y << 32) | av.x);
      acc0 = __builtin_amdgcn_mfma_f32_16x16x32_fp8_fp8(a, wf[0][ks], acc0, 0, 0, 0);
      acc1 = __builtin_amdgcn_mfma_f32_16x16x32_fp8_fp8(a, wf[1][ks], acc1, 0, 0, 0);
      acc2 = __builtin_amdgcn_mfma_f32_16x16x32_fp8_fp8(a, wf[2][ks], acc2, 0, 0, 0);
      acc3 = __builtin_amdgcn_mfma_f32_16x16x32_fp8_fp8(a, wf[3][ks], acc3, 0, 0, 0);
    }
    // prefetch next step's xp (consumed after next barrier)
    uint2 xpn;
    if (t < 511)
      xpn = *(const uint2*)(xp + ((size_t)(t + 1) * 128 + b0 + cb) * 1024 + ch * 4);
    // redistribute valid rows (0-3, held by lg==0 lanes) to gl[row][hcol][gate]
    if (lg == 0) {
#pragma unroll
      for (int i = 0; i < 4; ++i) {
        f32x4 wv;
        wv[0] = acc0[i]; wv[1] = acc1[i]; wv[2] = acc2[i]; wv[3] = acc3[i];
        *(f32x4*)(gl + ((i << 8) + hcol) * 4) = wv;
      }
    }
    __syncthreads();
    // ---- gate phase: one cell per thread ----
    f32x4 g4 = *(const f32x4*)(gl + ((cb << 8) + ch) * 4);
    union { uint2 u; ushort s[4]; } xv; xv.u = xpv;
    float gi = g4[0] * INV_SCALE + bf2f(xv.s[0]);
    float gf = g4[1] * INV_SCALE + bf2f(xv.s[1]);
    float gg = g4[2] * INV_SCALE + bf2f(xv.s[2]);
    float go = g4[3] * INV_SCALE + bf2f(xv.s[3]);
    float si = sigm(gi), sf = sigm(gf), so = sigm(go);
    float tg = tanh_(gg);
    cc = sf * cc + si * tg;
    float h = so * tanh_(cc);
    int q = __builtin_amdgcn_cvt_pk_fp8_f32(h * 16.f, h * 16.f, 0, false);
    hw[cb * 272 + ch] = (unsigned char)(q & 0xFF);
    if (!FINAL) {
      hs_out[((size_t)t * 128 + b0 + cb) * 256 + ch] = f2bf(h);
    } else if (t == 511) {
      hf[cb][ch] = h;
    }
    xpv = xpn;
    __syncthreads();
  }

  if (FINAL && w < 4) {
    float s = 0.f;
#pragma unroll
    for (int j = 0; j < 4; ++j) {
      const int k = j * 64 + l;
      s += hf[w][k] * fcw[k];
    }
    s += __shfl_xor(s, 1);
    s += __shfl_xor(s, 2);
    s += __shfl_xor(s, 4);
    s += __shfl_xor(s, 8);
    s += __shfl_xor(s, 16);
    s += __shfl_xor(s, 32);
    if (l == 0) out[b0 + w] = sigm(s + fcb[0]);
  }
}

// ---------------- launch ----------------
extern "C" void kernel_launch(void* const* d_in, const int* in_sizes, int n_in,
                              void* d_out, int out_size, void* d_ws, size_t ws_size,
                              hipStream_t stream)
{
  const int*   x    = (const int*)d_in[0];
  const float* emb  = (const float*)d_in[1];
  const float* fcw  = (const float*)d_in[2];
  const float* fcb  = (const float*)d_in[3];
  const float* Wih0 = (const float*)d_in[4];
  const float* Whh0 = (const float*)d_in[5];
  const float* bih0 = (const float*)d_in[6];
  const float* bhh0 = (const float*)d_in[7];
  const float* Wih1 = (const float*)d_in[8];
  const float* Whh1 = (const float*)d_in[9];
  const float* bih1 = (const float*)d_in[10];
  const float* bhh1 = (const float*)d_in[11];

  char* ws = (char*)d_ws;
  size_t off = 0;
  auto alloc = [&](size_t bytes) {
    void* p = ws + off;
    off = (off + bytes + 255) & ~(size_t)255;
    return p;
  };
  ushort* xp_ws  = (ushort*)alloc(65536ull * 1024 * 2);  // reused for xp0' then xp1'
  ushort* hs0    = (ushort*)alloc(65536ull * 256 * 2);
  ushort* emb_bf = (ushort*)alloc(32000ull * 128 * 2);
  ushort* W0p    = (ushort*)alloc(1024ull * 128 * 2);
  ushort* W1p    = (ushort*)alloc(1024ull * 256 * 2);
  float*  b0p    = (float*)alloc(1024 * 4);
  float*  b1p    = (float*)alloc(1024 * 4);
  int*    idx_ws = (int*)alloc(65536 * 4);

  prep_kernel<<<512, 256, 0, stream>>>(emb, x, Wih0, Wih1, bih0, bhh0, bih1, bhh1,
                                       emb_bf, idx_ws, W0p, W1p, b0p, b1p);
  gemm_xp<128, true><<<dim3(512, 8), 256, 0, stream>>>(emb_bf, idx_ws, W0p, b0p, xp_ws);
  lstm_scan<false><<<32, 1024, 0, stream>>>(xp_ws, Whh0, hs0, nullptr, nullptr, nullptr);
  gemm_xp<256, false><<<dim3(512, 8), 256, 0, stream>>>(hs0, nullptr, W1p, b1p, xp_ws);
  lstm_scan<true><<<32, 1024, 0, stream>>>(xp_ws, Whh1, nullptr, fcw, fcb, (float*)d_out);
}

// Round 4
// 1604.491 us; speedup vs baseline: 1.3916x; 1.1893x over previous
//
#include <hip/hip_runtime.h>
#include <hip/hip_bf16.h>
#include <stdint.h>

typedef float f32x4 __attribute__((ext_vector_type(4)));
typedef short s16x8 __attribute__((ext_vector_type(8)));

#define INV_SCALE (1.0f / 1024.0f)  // W pre-scaled x64, h x16

__device__ __forceinline__ float sigm(float x) {
  return __builtin_amdgcn_rcpf(1.f + __builtin_amdgcn_exp2f(-1.4426950408889634f * x));
}
__device__ __forceinline__ float tanh_(float x) {
  return 1.f - 2.f * __builtin_amdgcn_rcpf(__builtin_amdgcn_exp2f(2.8853900817779268f * x) + 1.f);
}
__device__ __forceinline__ ushort f2bf(float f) {
  union { float f; uint32_t u; } v; v.f = f;
  return (ushort)((v.u + 0x7FFFu + ((v.u >> 16) & 1)) >> 16);
}
__device__ __forceinline__ float bf2f(ushort b) {
  union { uint32_t u; float f; } v; v.u = ((uint32_t)b) << 16; return v.f;
}

// ---------------- prep: converts + permutes + transposes ----------------
__global__ __launch_bounds__(256) void prep_kernel(
    const float* __restrict__ emb, const int* __restrict__ x,
    const float* __restrict__ Wih0, const float* __restrict__ Wih1,
    const float* __restrict__ bih0, const float* __restrict__ bhh0,
    const float* __restrict__ bih1, const float* __restrict__ bhh1,
    ushort* __restrict__ emb_bf, int* __restrict__ idx_ws,
    ushort* __restrict__ W0p, ushort* __restrict__ W1p,
    float* __restrict__ b0p, float* __restrict__ b1p)
{
  const int stride = gridDim.x * blockDim.x;
  const int gid = blockIdx.x * blockDim.x + threadIdx.x;
  for (int i = gid; i < 32000 * 128; i += stride) emb_bf[i] = f2bf(emb[i]);
  // idx_ws[t*128+b] = x[b*512+t]
  for (int i = gid; i < 65536; i += stride) idx_ws[i] = x[(i & 127) * 512 + (i >> 7)];
  // W0p[j][k] = Wih0[(j&3)*256 + (j>>2)][k]   (j = hid*4 + gate)
  for (int i = gid; i < 1024 * 128; i += stride) {
    int j = i >> 7, k = i & 127;
    int p = ((j & 3) << 8) | (j >> 2);
    W0p[i] = f2bf(Wih0[p * 128 + k]);
  }
  for (int i = gid; i < 1024 * 256; i += stride) {
    int j = i >> 8, k = i & 255;
    int p = ((j & 3) << 8) | (j >> 2);
    W1p[i] = f2bf(Wih1[p * 256 + k]);
  }
  for (int i = gid; i < 1024; i += stride) {
    int p = ((i & 3) << 8) | (i >> 2);
    b0p[i] = bih0[p] + bhh0[p];
    b1p[i] = bih1[p] + bhh1[p];
  }
}

// ---------------- wide GEMM: xp[m][j] = A[m,:] @ Wp[j,:]^T + bias[j] ----------------
// M=65536 (m = t*128+b), N=1024 (interleaved j), K = 128 or 256. bf16 MFMA.
template <int KD, bool GATHER>
__global__ __launch_bounds__(256) void gemm_xp(
    const ushort* __restrict__ A, const int* __restrict__ idx,
    const ushort* __restrict__ B, const float* __restrict__ bias,
    ushort* __restrict__ out)
{
  __shared__ ushort Al[128 * 72];
  __shared__ ushort Bl[128 * 72];
  const int tid = threadIdx.x;
  const int l = tid & 63, w = tid >> 6;
  const int wm = w >> 1, wn = w & 1;
  const int lr = l & 15, lg = l >> 4;
  const int m0 = blockIdx.x * 128, n0 = blockIdx.y * 128;

  f32x4 acc[4][4];
#pragma unroll
  for (int a = 0; a < 4; ++a)
#pragma unroll
    for (int b = 0; b < 4; ++b) acc[a][b] = (f32x4)0.f;

  const int srow = tid >> 1, sseg = tid & 1;
  for (int kk = 0; kk < KD / 64; ++kk) {
    const int k0 = kk * 64;
    size_t arow = GATHER ? (size_t)idx[m0 + srow] : (size_t)(m0 + srow);
    const uint4* sa = (const uint4*)(A + arow * KD + k0 + sseg * 32);
    uint4* da = (uint4*)(Al + srow * 72 + sseg * 32);
    da[0] = sa[0]; da[1] = sa[1]; da[2] = sa[2]; da[3] = sa[3];
    const uint4* sb = (const uint4*)(B + (size_t)(n0 + srow) * KD + k0 + sseg * 32);
    uint4* db = (uint4*)(Bl + srow * 72 + sseg * 32);
    db[0] = sb[0]; db[1] = sb[1]; db[2] = sb[2]; db[3] = sb[3];
    __syncthreads();
#pragma unroll
    for (int ks = 0; ks < 2; ++ks) {
      s16x8 av[4], bv[4];
#pragma unroll
      for (int mt = 0; mt < 4; ++mt)
        av[mt] = *(const s16x8*)(Al + (wm * 64 + mt * 16 + lr) * 72 + ks * 32 + lg * 8);
#pragma unroll
      for (int nt = 0; nt < 4; ++nt)
        bv[nt] = *(const s16x8*)(Bl + (wn * 64 + nt * 16 + lr) * 72 + ks * 32 + lg * 8);
#pragma unroll
      for (int mt = 0; mt < 4; ++mt)
#pragma unroll
        for (int nt = 0; nt < 4; ++nt)
          acc[mt][nt] = __builtin_amdgcn_mfma_f32_16x16x32_bf16(av[mt], bv[nt], acc[mt][nt], 0, 0, 0);
    }
    __syncthreads();
  }

#pragma unroll
  for (int nt = 0; nt < 4; ++nt) {
    const int colg = n0 + wn * 64 + nt * 16 + lr;
    const float bv = bias[colg];
#pragma unroll
    for (int mt = 0; mt < 4; ++mt) {
#pragma unroll
      for (int i = 0; i < 4; ++i) {
        const int rowg = m0 + wm * 64 + mt * 16 + 4 * lg + i;
        out[(size_t)rowg * 1024 + colg] = f2bf(acc[mt][nt][i] + bv);
      }
    }
  }
}

// ---------------- LSTM scan: one WG = ONE batch, all 512 steps, 128 WGs ----------------
// W_hh register-resident as fp8 e4m3 (x64). h exchanged via LDS as fp8 (x16).
// MFMA output layout gives lane (lr, lg==0) ALL FOUR gates of cell col=16w+lr in
// acc0..3[0] -> gate math is lane-local, no redistribution, ONE barrier per step.
// All lanes run the gate math (rows 4/8/12 are zero-A garbage, bounded); writes masked.
template <bool FINAL>
__global__ __launch_bounds__(1024) void lstm_scan(
    const ushort* __restrict__ xp, const float* __restrict__ Whh,
    ushort* __restrict__ hs_out, const float* __restrict__ fcw,
    const float* __restrict__ fcb, float* __restrict__ out)
{
  __shared__ unsigned char hb[2][16 * 272];  // [buf][row][hidden fp8]; only row 0 live
  __shared__ float hf[260];                  // final-step f32 h (FINAL only)
  const int tid = threadIdx.x;
  const int l = tid & 63, w = tid >> 6;
  const int lr = l & 15, lg = l >> 4;
  const int b0 = blockIdx.x;  // one batch per WG
  const int hcol = 16 * w + lr;

  // Load W_hh fragments -> registers (fp8, x64). B-frag: n = gate*256 + hcol, k = ks*32+lg*8+j
  long wf[4][8];
#pragma unroll
  for (int s = 0; s < 4; ++s) {
    const int n = 256 * s + hcol;
#pragma unroll
    for (int ks = 0; ks < 8; ++ks) {
      const f32x4* p = (const f32x4*)(Whh + (size_t)n * 256 + ks * 32 + lg * 8);
      f32x4 w0 = p[0], w1 = p[1];
      int d0 = __builtin_amdgcn_cvt_pk_fp8_f32(w0.x * 64.f, w0.y * 64.f, 0, false);
      d0 = __builtin_amdgcn_cvt_pk_fp8_f32(w0.z * 64.f, w0.w * 64.f, d0, true);
      int d1 = __builtin_amdgcn_cvt_pk_fp8_f32(w1.x * 64.f, w1.y * 64.f, 0, false);
      d1 = __builtin_amdgcn_cvt_pk_fp8_f32(w1.z * 64.f, w1.w * 64.f, d1, true);
      wf[s][ks] = (long)(((unsigned long long)(unsigned)d1 << 32) | (unsigned)d0);
    }
  }

  for (int i2 = tid; i2 < 2 * 16 * 272; i2 += 1024) ((unsigned char*)hb)[i2] = 0;

  float cc = 0.f;
  uint2 xpv = *(const uint2*)(xp + (size_t)b0 * 1024 + hcol * 4);
  __syncthreads();

  for (int t = 0; t < 512; ++t) {
    const unsigned char* hr = hb[t & 1];
    unsigned char* hw = hb[(t & 1) ^ 1];
    // ---- MFMA phase: gates[0..3] for col hcol land in acc0..3[0] of lg==0 lanes ----
    f32x4 acc0 = (f32x4)0.f, acc1 = (f32x4)0.f, acc2 = (f32x4)0.f, acc3 = (f32x4)0.f;
#pragma unroll
    for (int ks = 0; ks < 8; ++ks) {
      uint2 av = *(const uint2*)(hr + lr * 272 + ks * 32 + lg * 8);
      long a = (long)(((unsigned long long)av.y << 32) | av.x);
      acc0 = __builtin_amdgcn_mfma_f32_16x16x32_fp8_fp8(a, wf[0][ks], acc0, 0, 0, 0);
      acc1 = __builtin_amdgcn_mfma_f32_16x16x32_fp8_fp8(a, wf[1][ks], acc1, 0, 0, 0);
      acc2 = __builtin_amdgcn_mfma_f32_16x16x32_fp8_fp8(a, wf[2][ks], acc2, 0, 0, 0);
      acc3 = __builtin_amdgcn_mfma_f32_16x16x32_fp8_fp8(a, wf[3][ks], acc3, 0, 0, 0);
    }
    // prefetch next step's xp (consumed next iteration)
    uint2 xpn;
    if (t < 511)
      xpn = *(const uint2*)(xp + ((size_t)(t + 1) * 128 + b0) * 1024 + hcol * 4);
    // ---- gate phase (all lanes; only lg==0 row-0 results are real) ----
    union { uint2 u; ushort s[4]; } xv; xv.u = xpv;
    float gi = acc0[0] * INV_SCALE + bf2f(xv.s[0]);
    float gf = acc1[0] * INV_SCALE + bf2f(xv.s[1]);
    float gg = acc2[0] * INV_SCALE + bf2f(xv.s[2]);
    float go = acc3[0] * INV_SCALE + bf2f(xv.s[3]);
    float si = sigm(gi), sf = sigm(gf), so = sigm(go);
    float tg = tanh_(gg);
    cc = sf * cc + si * tg;
    float h = so * tanh_(cc);
    if (lg == 0) {
      int q = __builtin_amdgcn_cvt_pk_fp8_f32(h * 16.f, h * 16.f, 0, false);
      hw[hcol] = (unsigned char)(q & 0xFF);
      if (!FINAL) {
        hs_out[((size_t)t * 128 + b0) * 256 + hcol] = f2bf(h);
      } else if (t == 511) {
        hf[hcol] = h;
      }
    }
    xpv = xpn;
    __syncthreads();
  }

  if (FINAL && w == 0) {
    float s = 0.f;
#pragma unroll
    for (int j = 0; j < 4; ++j) {
      const int k = j * 64 + l;
      s += hf[k] * fcw[k];
    }
    s += __shfl_xor(s, 1);
    s += __shfl_xor(s, 2);
    s += __shfl_xor(s, 4);
    s += __shfl_xor(s, 8);
    s += __shfl_xor(s, 16);
    s += __shfl_xor(s, 32);
    if (l == 0) out[b0] = sigm(s + fcb[0]);
  }
}

// ---------------- launch ----------------
extern "C" void kernel_launch(void* const* d_in, const int* in_sizes, int n_in,
                              void* d_out, int out_size, void* d_ws, size_t ws_size,
                              hipStream_t stream)
{
  const int*   x    = (const int*)d_in[0];
  const float* emb  = (const float*)d_in[1];
  const float* fcw  = (const float*)d_in[2];
  const float* fcb  = (const float*)d_in[3];
  const float* Wih0 = (const float*)d_in[4];
  const float* Whh0 = (const float*)d_in[5];
  const float* bih0 = (const float*)d_in[6];
  const float* bhh0 = (const float*)d_in[7];
  const float* Wih1 = (const float*)d_in[8];
  const float* Whh1 = (const float*)d_in[9];
  const float* bih1 = (const float*)d_in[10];
  const float* bhh1 = (const float*)d_in[11];

  char* ws = (char*)d_ws;
  size_t off = 0;
  auto alloc = [&](size_t bytes) {
    void* p = ws + off;
    off = (off + bytes + 255) & ~(size_t)255;
    return p;
  };
  ushort* xp_ws  = (ushort*)alloc(65536ull * 1024 * 2);  // reused for xp0' then xp1'
  ushort* hs0    = (ushort*)alloc(65536ull * 256 * 2);
  ushort* emb_bf = (ushort*)alloc(32000ull * 128 * 2);
  ushort* W0p    = (ushort*)alloc(1024ull * 128 * 2);
  ushort* W1p    = (ushort*)alloc(1024ull * 256 * 2);
  float*  b0p    = (float*)alloc(1024 * 4);
  float*  b1p    = (float*)alloc(1024 * 4);
  int*    idx_ws = (int*)alloc(65536 * 4);

  prep_kernel<<<512, 256, 0, stream>>>(emb, x, Wih0, Wih1, bih0, bhh0, bih1, bhh1,
                                       emb_bf, idx_ws, W0p, W1p, b0p, b1p);
  gemm_xp<128, true><<<dim3(512, 8), 256, 0, stream>>>(emb_bf, idx_ws, W0p, b0p, xp_ws);
  lstm_scan<false><<<128, 1024, 0, stream>>>(xp_ws, Whh0, hs0, nullptr, nullptr, nullptr);
  gemm_xp<256, false><<<dim3(512, 8), 256, 0, stream>>>(hs0, nullptr, W1p, b1p, xp_ws);
  lstm_scan<true><<<128, 1024, 0, stream>>>(xp_ws, Whh1, nullptr, fcw, fcb, (float*)d_out);
}

// Round 5
// 1173.983 us; speedup vs baseline: 1.9019x; 1.3667x over previous
//
#include <hip/hip_runtime.h>
#include <hip/hip_bf16.h>
#include <stdint.h>

typedef float f32x4 __attribute__((ext_vector_type(4)));
typedef short s16x8 __attribute__((ext_vector_type(8)));
typedef int i32x8 __attribute__((ext_vector_type(8)));

#define INV_SCALE (1.0f / 1024.0f)  // W pre-scaled x64, h x16
#define SCALE_ONE 0x7F7F7F7F        // E8M0 1.0 in every byte

__device__ __forceinline__ float sigm(float x) {
  return __builtin_amdgcn_rcpf(1.f + __builtin_amdgcn_exp2f(-1.4426950408889634f * x));
}
__device__ __forceinline__ float tanh_(float x) {
  return 1.f - 2.f * __builtin_amdgcn_rcpf(__builtin_amdgcn_exp2f(2.8853900817779268f * x) + 1.f);
}
__device__ __forceinline__ ushort f2bf(float f) {
  union { float f; uint32_t u; } v; v.f = f;
  return (ushort)((v.u + 0x7FFFu + ((v.u >> 16) & 1)) >> 16);
}
__device__ __forceinline__ float bf2f(ushort b) {
  union { uint32_t u; float f; } v; v.u = ((uint32_t)b) << 16; return v.f;
}

// ---------------- prep: converts + permutes + transposes ----------------
__global__ __launch_bounds__(256) void prep_kernel(
    const float* __restrict__ emb, const int* __restrict__ x,
    const float* __restrict__ Wih0, const float* __restrict__ Wih1,
    const float* __restrict__ bih0, const float* __restrict__ bhh0,
    const float* __restrict__ bih1, const float* __restrict__ bhh1,
    ushort* __restrict__ emb_bf, int* __restrict__ idx_ws,
    ushort* __restrict__ W0p, ushort* __restrict__ W1p,
    float* __restrict__ b0p, float* __restrict__ b1p)
{
  const int stride = gridDim.x * blockDim.x;
  const int gid = blockIdx.x * blockDim.x + threadIdx.x;
  for (int i = gid; i < 32000 * 128; i += stride) emb_bf[i] = f2bf(emb[i]);
  // idx_ws[t*128+b] = x[b*512+t]
  for (int i = gid; i < 65536; i += stride) idx_ws[i] = x[(i & 127) * 512 + (i >> 7)];
  // W0p[j][k] = Wih0[(j&3)*256 + (j>>2)][k]   (j = hid*4 + gate)
  for (int i = gid; i < 1024 * 128; i += stride) {
    int j = i >> 7, k = i & 127;
    int p = ((j & 3) << 8) | (j >> 2);
    W0p[i] = f2bf(Wih0[p * 128 + k]);
  }
  for (int i = gid; i < 1024 * 256; i += stride) {
    int j = i >> 8, k = i & 255;
    int p = ((j & 3) << 8) | (j >> 2);
    W1p[i] = f2bf(Wih1[p * 256 + k]);
  }
  for (int i = gid; i < 1024; i += stride) {
    int p = ((i & 3) << 8) | (i >> 2);
    b0p[i] = bih0[p] + bhh0[p];
    b1p[i] = bih1[p] + bhh1[p];
  }
}

// ---------------- wide GEMM: xp[m][j] = A[m,:] @ Wp[j,:]^T + bias[j] ----------------
// M=65536 (m = t*128+b), N=1024 (interleaved j), K = 128 or 256. bf16 MFMA.
template <int KD, bool GATHER>
__global__ __launch_bounds__(256) void gemm_xp(
    const ushort* __restrict__ A, const int* __restrict__ idx,
    const ushort* __restrict__ B, const float* __restrict__ bias,
    ushort* __restrict__ out)
{
  __shared__ ushort Al[128 * 72];
  __shared__ ushort Bl[128 * 72];
  const int tid = threadIdx.x;
  const int l = tid & 63, w = tid >> 6;
  const int wm = w >> 1, wn = w & 1;
  const int lr = l & 15, lg = l >> 4;
  const int m0 = blockIdx.x * 128, n0 = blockIdx.y * 128;

  f32x4 acc[4][4];
#pragma unroll
  for (int a = 0; a < 4; ++a)
#pragma unroll
    for (int b = 0; b < 4; ++b) acc[a][b] = (f32x4)0.f;

  const int srow = tid >> 1, sseg = tid & 1;
  for (int kk = 0; kk < KD / 64; ++kk) {
    const int k0 = kk * 64;
    size_t arow = GATHER ? (size_t)idx[m0 + srow] : (size_t)(m0 + srow);
    const uint4* sa = (const uint4*)(A + arow * KD + k0 + sseg * 32);
    uint4* da = (uint4*)(Al + srow * 72 + sseg * 32);
    da[0] = sa[0]; da[1] = sa[1]; da[2] = sa[2]; da[3] = sa[3];
    const uint4* sb = (const uint4*)(B + (size_t)(n0 + srow) * KD + k0 + sseg * 32);
    uint4* db = (uint4*)(Bl + srow * 72 + sseg * 32);
    db[0] = sb[0]; db[1] = sb[1]; db[2] = sb[2]; db[3] = sb[3];
    __syncthreads();
#pragma unroll
    for (int ks = 0; ks < 2; ++ks) {
      s16x8 av[4], bv[4];
#pragma unroll
      for (int mt = 0; mt < 4; ++mt)
        av[mt] = *(const s16x8*)(Al + (wm * 64 + mt * 16 + lr) * 72 + ks * 32 + lg * 8);
#pragma unroll
      for (int nt = 0; nt < 4; ++nt)
        bv[nt] = *(const s16x8*)(Bl + (wn * 64 + nt * 16 + lr) * 72 + ks * 32 + lg * 8);
#pragma unroll
      for (int mt = 0; mt < 4; ++mt)
#pragma unroll
        for (int nt = 0; nt < 4; ++nt)
          acc[mt][nt] = __builtin_amdgcn_mfma_f32_16x16x32_bf16(av[mt], bv[nt], acc[mt][nt], 0, 0, 0);
    }
    __syncthreads();
  }

#pragma unroll
  for (int nt = 0; nt < 4; ++nt) {
    const int colg = n0 + wn * 64 + nt * 16 + lr;
    const float bv = bias[colg];
#pragma unroll
    for (int mt = 0; mt < 4; ++mt) {
#pragma unroll
      for (int i = 0; i < 4; ++i) {
        const int rowg = m0 + wm * 64 + mt * 16 + 4 * lg + i;
        out[(size_t)rowg * 1024 + colg] = f2bf(acc[mt][nt][i] + bv);
      }
    }
  }
}

// ---------------- LSTM scan: one WG = ONE batch, 128 WGs, MX K=128 fp8 MFMA ----------------
// W_hh register-resident as fp8 e4m3 (x64), consumed via mfma_scale_f32_16x16x128_f8f6f4
// with unit scales. h broadcast: ALL A-lanes read the same 32B k-block of h (rows 0-15
// identical) -> conflict-free LDS reads, row 0 of C = real gates, lane-local in lg==0.
// One barrier per step.
template <bool FINAL>
__global__ __launch_bounds__(1024) void lstm_scan(
    const ushort* __restrict__ xp, const float* __restrict__ Whh,
    ushort* __restrict__ hs_out, const float* __restrict__ fcw,
    const float* __restrict__ fcb, float* __restrict__ out)
{
  __shared__ unsigned char hb[2][320];  // [buf][hidden fp8], one batch
  __shared__ float hf[260];             // final-step f32 h (FINAL only)
  const int tid = threadIdx.x;
  const int l = tid & 63, w = tid >> 6;
  const int lr = l & 15, lg = l >> 4;
  const int b0 = blockIdx.x;  // one batch per WG
  const int hcol = 16 * w + lr;

  // W_hh fragments (fp8 x64): gate s, k-chunk kc; B col = 256*s + hcol, k = kc*128 + lg*32 + j
  i32x8 wf[4][2];
#pragma unroll
  for (int s = 0; s < 4; ++s) {
    const int n = 256 * s + hcol;
#pragma unroll
    for (int kc = 0; kc < 2; ++kc) {
      i32x8 r;
#pragma unroll
      for (int d = 0; d < 8; ++d) {
        const f32x4 v = *(const f32x4*)(Whh + (size_t)n * 256 + kc * 128 + lg * 32 + d * 4);
        int q = __builtin_amdgcn_cvt_pk_fp8_f32(v[0] * 64.f, v[1] * 64.f, 0, false);
        q = __builtin_amdgcn_cvt_pk_fp8_f32(v[2] * 64.f, v[3] * 64.f, q, true);
        r[d] = q;
      }
      wf[s][kc] = r;
    }
  }

  if (tid < 320) hb[0][tid] = 0;  // h(-1) = 0

  float cc = 0.f;
  uint2 xpv = *(const uint2*)(xp + (size_t)b0 * 1024 + hcol * 4);
  __syncthreads();

  for (int t = 0; t < 512; ++t) {
    const unsigned char* hr = hb[t & 1];
    unsigned char* hw = hb[(t & 1) ^ 1];
    // ---- A fragments: broadcast (lr-independent) -> conflict-free ----
    i32x8 af[2];
#pragma unroll
    for (int kc = 0; kc < 2; ++kc) {
      const uint4* p = (const uint4*)(hr + kc * 128 + lg * 32);
      uint4 lo = p[0], hi = p[1];
      i32x8 a;
      a[0] = lo.x; a[1] = lo.y; a[2] = lo.z; a[3] = lo.w;
      a[4] = hi.x; a[5] = hi.y; a[6] = hi.z; a[7] = hi.w;
      af[kc] = a;
    }
    // ---- MFMA phase: 8 x K=128 MX fp8 (unit scales) ----
    f32x4 acc0 = (f32x4)0.f, acc1 = (f32x4)0.f, acc2 = (f32x4)0.f, acc3 = (f32x4)0.f;
#pragma unroll
    for (int kc = 0; kc < 2; ++kc) {
      acc0 = __builtin_amdgcn_mfma_scale_f32_16x16x128_f8f6f4(af[kc], wf[0][kc], acc0, 0, 0, 0, SCALE_ONE, 0, SCALE_ONE);
      acc1 = __builtin_amdgcn_mfma_scale_f32_16x16x128_f8f6f4(af[kc], wf[1][kc], acc1, 0, 0, 0, SCALE_ONE, 0, SCALE_ONE);
      acc2 = __builtin_amdgcn_mfma_scale_f32_16x16x128_f8f6f4(af[kc], wf[2][kc], acc2, 0, 0, 0, SCALE_ONE, 0, SCALE_ONE);
      acc3 = __builtin_amdgcn_mfma_scale_f32_16x16x128_f8f6f4(af[kc], wf[3][kc], acc3, 0, 0, 0, SCALE_ONE, 0, SCALE_ONE);
    }
    // prefetch next step's xp (consumed next iteration)
    uint2 xpn;
    if (t < 511)
      xpn = *(const uint2*)(xp + ((size_t)(t + 1) * 128 + b0) * 1024 + hcol * 4);
    // ---- gate phase (all lanes compute; only lg==0 writes are real) ----
    union { uint2 u; ushort s[4]; } xv; xv.u = xpv;
    float gi = acc0[0] * INV_SCALE + bf2f(xv.s[0]);
    float gf = acc1[0] * INV_SCALE + bf2f(xv.s[1]);
    float gg = acc2[0] * INV_SCALE + bf2f(xv.s[2]);
    float go = acc3[0] * INV_SCALE + bf2f(xv.s[3]);
    float si = sigm(gi), sf = sigm(gf), so = sigm(go);
    float tg = tanh_(gg);
    cc = sf * cc + si * tg;
    float h = so * tanh_(cc);
    if (lg == 0) {
      int q = __builtin_amdgcn_cvt_pk_fp8_f32(h * 16.f, h * 16.f, 0, false);
      hw[hcol] = (unsigned char)(q & 0xFF);
      if (!FINAL) {
        hs_out[((size_t)t * 128 + b0) * 256 + hcol] = f2bf(h);
      } else if (t == 511) {
        hf[hcol] = h;
      }
    }
    xpv = xpn;
    __syncthreads();
  }

  if (FINAL && w == 0) {
    float s = 0.f;
#pragma unroll
    for (int j = 0; j < 4; ++j) {
      const int k = j * 64 + l;
      s += hf[k] * fcw[k];
    }
    s += __shfl_xor(s, 1);
    s += __shfl_xor(s, 2);
    s += __shfl_xor(s, 4);
    s += __shfl_xor(s, 8);
    s += __shfl_xor(s, 16);
    s += __shfl_xor(s, 32);
    if (l == 0) out[b0] = sigm(s + fcb[0]);
  }
}

// ---------------- launch ----------------
extern "C" void kernel_launch(void* const* d_in, const int* in_sizes, int n_in,
                              void* d_out, int out_size, void* d_ws, size_t ws_size,
                              hipStream_t stream)
{
  const int*   x    = (const int*)d_in[0];
  const float* emb  = (const float*)d_in[1];
  const float* fcw  = (const float*)d_in[2];
  const float* fcb  = (const float*)d_in[3];
  const float* Wih0 = (const float*)d_in[4];
  const float* Whh0 = (const float*)d_in[5];
  const float* bih0 = (const float*)d_in[6];
  const float* bhh0 = (const float*)d_in[7];
  const float* Wih1 = (const float*)d_in[8];
  const float* Whh1 = (const float*)d_in[9];
  const float* bih1 = (const float*)d_in[10];
  const float* bhh1 = (const float*)d_in[11];

  char* ws = (char*)d_ws;
  size_t off = 0;
  auto alloc = [&](size_t bytes) {
    void* p = ws + off;
    off = (off + bytes + 255) & ~(size_t)255;
    return p;
  };
  ushort* xp_ws  = (ushort*)alloc(65536ull * 1024 * 2);  // reused for xp0' then xp1'
  ushort* hs0    = (ushort*)alloc(65536ull * 256 * 2);
  ushort* emb_bf = (ushort*)alloc(32000ull * 128 * 2);
  ushort* W0p    = (ushort*)alloc(1024ull * 128 * 2);
  ushort* W1p    = (ushort*)alloc(1024ull * 256 * 2);
  float*  b0p    = (float*)alloc(1024 * 4);
  float*  b1p    = (float*)alloc(1024 * 4);
  int*    idx_ws = (int*)alloc(65536 * 4);

  prep_kernel<<<512, 256, 0, stream>>>(emb, x, Wih0, Wih1, bih0, bhh0, bih1, bhh1,
                                       emb_bf, idx_ws, W0p, W1p, b0p, b1p);
  gemm_xp<128, true><<<dim3(512, 8), 256, 0, stream>>>(emb_bf, idx_ws, W0p, b0p, xp_ws);
  lstm_scan<false><<<128, 1024, 0, stream>>>(xp_ws, Whh0, hs0, nullptr, nullptr, nullptr);
  gemm_xp<256, false><<<dim3(512, 8), 256, 0, stream>>>(hs0, nullptr, W1p, b1p, xp_ws);
  lstm_scan<true><<<128, 1024, 0, stream>>>(xp_ws, Whh1, nullptr, fcw, fcb, (float*)d_out);
}

// Round 7
// 1120.217 us; speedup vs baseline: 1.9932x; 1.0480x over previous
//
#include <hip/hip_runtime.h>
#include <hip/hip_bf16.h>
#include <stdint.h>

typedef float f32x4 __attribute__((ext_vector_type(4)));
typedef short s16x8 __attribute__((ext_vector_type(8)));
typedef int i32x8 __attribute__((ext_vector_type(8)));

#define INV_SCALE (1.0f / 1024.0f)  // W pre-scaled x64, h x16
#define SCALE_ONE 0x7F7F7F7F        // E8M0 1.0 in every byte
#define LOG2E 1.4426950408889634f

__device__ __forceinline__ float sigm(float x) {
  return __builtin_amdgcn_rcpf(1.f + __builtin_amdgcn_exp2f(-LOG2E * x));
}
__device__ __forceinline__ ushort f2bf(float f) {
  union { float f; uint32_t u; } v; v.f = f;
  return (ushort)((v.u + 0x7FFFu + ((v.u >> 16) & 1)) >> 16);
}
__device__ __forceinline__ float bf2f(ushort b) {
  union { uint32_t u; float f; } v; v.u = ((uint32_t)b) << 16; return v.f;
}

// ---------------- prep: converts + permutes + transposes ----------------
__global__ __launch_bounds__(256) void prep_kernel(
    const float* __restrict__ emb, const int* __restrict__ x,
    const float* __restrict__ Wih0, const float* __restrict__ Wih1,
    const float* __restrict__ bih0, const float* __restrict__ bhh0,
    const float* __restrict__ bih1, const float* __restrict__ bhh1,
    ushort* __restrict__ emb_bf, int* __restrict__ idx_ws,
    ushort* __restrict__ W0p, ushort* __restrict__ W1p,
    float* __restrict__ b0p, float* __restrict__ b1p)
{
  const int stride = gridDim.x * blockDim.x;
  const int gid = blockIdx.x * blockDim.x + threadIdx.x;
  for (int i = gid; i < 32000 * 128; i += stride) emb_bf[i] = f2bf(emb[i]);
  // idx_ws[t*128+b] = x[b*512+t]
  for (int i = gid; i < 65536; i += stride) idx_ws[i] = x[(i & 127) * 512 + (i >> 7)];
  // W0p[j][k] = Wih0[(j&3)*256 + (j>>2)][k]   (j = hid*4 + gate)
  for (int i = gid; i < 1024 * 128; i += stride) {
    int j = i >> 7, k = i & 127;
    int p = ((j & 3) << 8) | (j >> 2);
    W0p[i] = f2bf(Wih0[p * 128 + k]);
  }
  for (int i = gid; i < 1024 * 256; i += stride) {
    int j = i >> 8, k = i & 255;
    int p = ((j & 3) << 8) | (j >> 2);
    W1p[i] = f2bf(Wih1[p * 256 + k]);
  }
  for (int i = gid; i < 1024; i += stride) {
    int p = ((i & 3) << 8) | (i >> 2);
    b0p[i] = bih0[p] + bhh0[p];
    b1p[i] = bih1[p] + bhh1[p];
  }
}

// ---------------- wide GEMM: xp[m][j] = A[m,:] @ Wp[j,:]^T + bias[j] ----------------
// M=65536 (m = t*128+b), N=1024 (interleaved j), K = 128 or 256. bf16 MFMA.
template <int KD, bool GATHER>
__global__ __launch_bounds__(256) void gemm_xp(
    const ushort* __restrict__ A, const int* __restrict__ idx,
    const ushort* __restrict__ B, const float* __restrict__ bias,
    ushort* __restrict__ out)
{
  __shared__ ushort Al[128 * 72];
  __shared__ ushort Bl[128 * 72];
  const int tid = threadIdx.x;
  const int l = tid & 63, w = tid >> 6;
  const int wm = w >> 1, wn = w & 1;
  const int lr = l & 15, lg = l >> 4;
  const int m0 = blockIdx.x * 128, n0 = blockIdx.y * 128;

  f32x4 acc[4][4];
#pragma unroll
  for (int a = 0; a < 4; ++a)
#pragma unroll
    for (int b = 0; b < 4; ++b) acc[a][b] = (f32x4)0.f;

  const int srow = tid >> 1, sseg = tid & 1;
  for (int kk = 0; kk < KD / 64; ++kk) {
    const int k0 = kk * 64;
    size_t arow = GATHER ? (size_t)idx[m0 + srow] : (size_t)(m0 + srow);
    const uint4* sa = (const uint4*)(A + arow * KD + k0 + sseg * 32);
    uint4* da = (uint4*)(Al + srow * 72 + sseg * 32);
    da[0] = sa[0]; da[1] = sa[1]; da[2] = sa[2]; da[3] = sa[3];
    const uint4* sb = (const uint4*)(B + (size_t)(n0 + srow) * KD + k0 + sseg * 32);
    uint4* db = (uint4*)(Bl + srow * 72 + sseg * 32);
    db[0] = sb[0]; db[1] = sb[1]; db[2] = sb[2]; db[3] = sb[3];
    __syncthreads();
#pragma unroll
    for (int ks = 0; ks < 2; ++ks) {
      s16x8 av[4], bv[4];
#pragma unroll
      for (int mt = 0; mt < 4; ++mt)
        av[mt] = *(const s16x8*)(Al + (wm * 64 + mt * 16 + lr) * 72 + ks * 32 + lg * 8);
#pragma unroll
      for (int nt = 0; nt < 4; ++nt)
        bv[nt] = *(const s16x8*)(Bl + (wn * 64 + nt * 16 + lr) * 72 + ks * 32 + lg * 8);
#pragma unroll
      for (int mt = 0; mt < 4; ++mt)
#pragma unroll
        for (int nt = 0; nt < 4; ++nt)
          acc[mt][nt] = __builtin_amdgcn_mfma_f32_16x16x32_bf16(av[mt], bv[nt], acc[mt][nt], 0, 0, 0);
    }
    __syncthreads();
  }

#pragma unroll
  for (int nt = 0; nt < 4; ++nt) {
    const int colg = n0 + wn * 64 + nt * 16 + lr;
    const float bv = bias[colg];
#pragma unroll
    for (int mt = 0; mt < 4; ++mt) {
#pragma unroll
      for (int i = 0; i < 4; ++i) {
        const int rowg = m0 + wm * 64 + mt * 16 + 4 * lg + i;
        out[(size_t)rowg * 1024 + colg] = f2bf(acc[mt][nt][i] + bv);
      }
    }
  }
}

// ---------------- LSTM scan: one WG = ONE batch, 128 WGs, MX K=128 fp8 MFMA ----------------
// W_hh register-resident as fp8 e4m3 (x64) via mfma_scale_f32_16x16x128 (unit scales);
// h broadcast from 320B ping-pong LDS buffers (conflict-free). Gate phase is lg-split:
// broadcast-A makes every lane hold ALL FOUR gate pre-activations (acc0..3[0]); lane
// group lg computes only gate lg's nonlinearity via the unified form 1 - m*rcp(exp2(k*p)+1)
// (sigmoid: k=log2e,m=1; tanh: k=2log2e,m=2), then 3 __shfl's combine sf/tg/so into lg0
// for the short serial chain. 2 transcendentals/lane instead of 10. One barrier per step.
template <bool FINAL>
__global__ __launch_bounds__(1024) void lstm_scan(
    const ushort* __restrict__ xp, const float* __restrict__ Whh,
    ushort* __restrict__ hs_out, const float* __restrict__ fcw,
    const float* __restrict__ fcb, float* __restrict__ out)
{
  __shared__ unsigned char hb[2][320];  // [buf][hidden fp8], one batch
  __shared__ float hf[260];             // final-step f32 h (FINAL only)
  const int tid = threadIdx.x;
  const int l = tid & 63, w = tid >> 6;
  const int lr = l & 15, lg = l >> 4;
  const int b0 = blockIdx.x;  // one batch per WG
  const int hcol = 16 * w + lr;

  // W_hh fragments (fp8 x64): gate s, k-chunk kc; B col = 256*s + hcol, k = kc*128 + lg*32 + j
  i32x8 wf[4][2];
#pragma unroll
  for (int s = 0; s < 4; ++s) {
    const int n = 256 * s + hcol;
#pragma unroll
    for (int kc = 0; kc < 2; ++kc) {
      i32x8 r;
#pragma unroll
      for (int d = 0; d < 8; ++d) {
        const f32x4 v = *(const f32x4*)(Whh + (size_t)n * 256 + kc * 128 + lg * 32 + d * 4);
        int q = __builtin_amdgcn_cvt_pk_fp8_f32(v[0] * 64.f, v[1] * 64.f, 0, false);
        q = __builtin_amdgcn_cvt_pk_fp8_f32(v[2] * 64.f, v[3] * 64.f, q, true);
        r[d] = q;
      }
      wf[s][kc] = r;
    }
  }

  if (tid < 320) hb[0][tid] = 0;  // h(-1) = 0

  float cc = 0.f;
  uint2 xpv = *(const uint2*)(xp + (size_t)b0 * 1024 + hcol * 4);
  __syncthreads();

  for (int t = 0; t < 512; ++t) {
    const unsigned char* hr = hb[t & 1];
    unsigned char* hw = hb[(t & 1) ^ 1];
    // ---- A fragments: broadcast (lr-independent) -> conflict-free ----
    i32x8 af[2];
#pragma unroll
    for (int kc = 0; kc < 2; ++kc) {
      const uint4* p = (const uint4*)(hr + kc * 128 + lg * 32);
      uint4 lo = p[0], hi = p[1];
      i32x8 a;
      a[0] = lo.x; a[1] = lo.y; a[2] = lo.z; a[3] = lo.w;
      a[4] = hi.x; a[5] = hi.y; a[6] = hi.z; a[7] = hi.w;
      af[kc] = a;
    }
    // ---- MFMA phase: 8 x K=128 MX fp8 (unit scales) ----
    f32x4 acc0 = (f32x4)0.f, acc1 = (f32x4)0.f, acc2 = (f32x4)0.f, acc3 = (f32x4)0.f;
#pragma unroll
    for (int kc = 0; kc < 2; ++kc) {
      acc0 = __builtin_amdgcn_mfma_scale_f32_16x16x128_f8f6f4(af[kc], wf[0][kc], acc0, 0, 0, 0, SCALE_ONE, 0, SCALE_ONE);
      acc1 = __builtin_amdgcn_mfma_scale_f32_16x16x128_f8f6f4(af[kc], wf[1][kc], acc1, 0, 0, 0, SCALE_ONE, 0, SCALE_ONE);
      acc2 = __builtin_amdgcn_mfma_scale_f32_16x16x128_f8f6f4(af[kc], wf[2][kc], acc2, 0, 0, 0, SCALE_ONE, 0, SCALE_ONE);
      acc3 = __builtin_amdgcn_mfma_scale_f32_16x16x128_f8f6f4(af[kc], wf[3][kc], acc3, 0, 0, 0, SCALE_ONE, 0, SCALE_ONE);
    }
    // prefetch next step's xp (consumed next iteration)
    uint2 xpn;
    if (t < 511)
      xpn = *(const uint2*)(xp + ((size_t)(t + 1) * 128 + b0) * 1024 + hcol * 4);
    // ---- gate phase: lg-specialized nonlinearity, shuffle-combined into lg0 ----
    // lane (lr,lg) computes gate lg's nonlinearity for col hcol (rows identical by broadcast)
    const uint word = (lg & 2) ? xpv.y : xpv.x;
    const uint h16 = (lg & 1) ? (word >> 16) : (word & 0xFFFFu);
    union { uint32_t u; float f; } xf; xf.u = h16 << 16;
    const float accsel = (lg & 2) ? ((lg & 1) ? acc3[0] : acc2[0])
                                  : ((lg & 1) ? acc1[0] : acc0[0]);
    const float p = accsel * INV_SCALE + xf.f;
    const float kk = (lg == 2) ? (2.f * LOG2E) : LOG2E;
    const float mm = (lg == 2) ? 2.f : 1.f;
    const float ex = __builtin_amdgcn_exp2f(kk * p);
    const float v = 1.f - mm * __builtin_amdgcn_rcpf(ex + 1.f);  // sigm or tanh of p
    const float sf = __shfl(v, lr + 16);
    const float tg = __shfl(v, lr + 32);
    const float so = __shfl(v, lr + 48);
    cc = sf * cc + v * tg;  // v = si in lg0 lanes
    const float e2 = __builtin_amdgcn_exp2f(2.f * LOG2E * cc);
    const float th = 1.f - 2.f * __builtin_amdgcn_rcpf(e2 + 1.f);
    const float h = so * th;
    if (lg == 0) {
      int q = __builtin_amdgcn_cvt_pk_fp8_f32(h * 16.f, h * 16.f, 0, false);
      hw[hcol] = (unsigned char)(q & 0xFF);
      if (!FINAL) {
        hs_out[((size_t)t * 128 + b0) * 256 + hcol] = f2bf(h);
      } else if (t == 511) {
        hf[hcol] = h;
      }
    }
    xpv = xpn;
    __syncthreads();
  }

  if (FINAL && w == 0) {
    float s = 0.f;
#pragma unroll
    for (int j = 0; j < 4; ++j) {
      const int k = j * 64 + l;
      s += hf[k] * fcw[k];
    }
    s += __shfl_xor(s, 1);
    s += __shfl_xor(s, 2);
    s += __shfl_xor(s, 4);
    s += __shfl_xor(s, 8);
    s += __shfl_xor(s, 16);
    s += __shfl_xor(s, 32);
    if (l == 0) out[b0] = sigm(s + fcb[0]);
  }
}

// ---------------- launch ----------------
extern "C" void kernel_launch(void* const* d_in, const int* in_sizes, int n_in,
                              void* d_out, int out_size, void* d_ws, size_t ws_size,
                              hipStream_t stream)
{
  const int*   x    = (const int*)d_in[0];
  const float* emb  = (const float*)d_in[1];
  const float* fcw  = (const float*)d_in[2];
  const float* fcb  = (const float*)d_in[3];
  const float* Wih0 = (const float*)d_in[4];
  const float* Whh0 = (const float*)d_in[5];
  const float* bih0 = (const float*)d_in[6];
  const float* bhh0 = (const float*)d_in[7];
  const float* Wih1 = (const float*)d_in[8];
  const float* Whh1 = (const float*)d_in[9];
  const float* bih1 = (const float*)d_in[10];
  const float* bhh1 = (const float*)d_in[11];

  char* ws = (char*)d_ws;
  size_t off = 0;
  auto alloc = [&](size_t bytes) {
    void* p = ws + off;
    off = (off + bytes + 255) & ~(size_t)255;
    return p;
  };
  ushort* xp_ws  = (ushort*)alloc(65536ull * 1024 * 2);  // reused for xp0' then xp1'
  ushort* hs0    = (ushort*)alloc(65536ull * 256 * 2);
  ushort* emb_bf = (ushort*)alloc(32000ull * 128 * 2);
  ushort* W0p    = (ushort*)alloc(1024ull * 128 * 2);
  ushort* W1p    = (ushort*)alloc(1024ull * 256 * 2);
  float*  b0p    = (float*)alloc(1024 * 4);
  float*  b1p    = (float*)alloc(1024 * 4);
  int*    idx_ws = (int*)alloc(65536 * 4);

  prep_kernel<<<512, 256, 0, stream>>>(emb, x, Wih0, Wih1, bih0, bhh0, bih1, bhh1,
                                       emb_bf, idx_ws, W0p, W1p, b0p, b1p);
  gemm_xp<128, true><<<dim3(512, 8), 256, 0, stream>>>(emb_bf, idx_ws, W0p, b0p, xp_ws);
  lstm_scan<false><<<128, 1024, 0, stream>>>(xp_ws, Whh0, hs0, nullptr, nullptr, nullptr);
  gemm_xp<256, false><<<dim3(512, 8), 256, 0, stream>>>(hs0, nullptr, W1p, b1p, xp_ws);
  lstm_scan<true><<<128, 1024, 0, stream>>>(xp_ws, Whh1, nullptr, fcw, fcb, (float*)d_out);
}